// Round 1
// baseline (3127.771 us; speedup 1.0000x reference)
//
#include <hip/hip_runtime.h>
#include <math.h>

#define T_TOK 1024
#define DIM   2048
#define NHQ   16
#define NHKV  4
#define HD    128
#define QKV_N 3072      // (16+2*4)*128
#define NE    8
#define NF    768
#define EPSF  1e-6f

typedef __attribute__((ext_vector_type(4))) float f32x4;
typedef __attribute__((ext_vector_type(8))) short s16x8;

// float -> bf16 bits, round-to-nearest-even
__device__ __forceinline__ unsigned short f2bf(float f) {
    union { float f; unsigned u; } v; v.f = f;
    unsigned u = v.u;
    return (unsigned short)((u + 0x7fffu + ((u >> 16) & 1u)) >> 16);
}
__device__ __forceinline__ float bf2f(unsigned short h) {
    union { unsigned u; float f; } v; v.u = ((unsigned)h) << 16;
    return v.f;
}

// ============================= embedding gather =============================
__global__ __launch_bounds__(256) void k_embed(const float* __restrict__ embed,
                                               const int* __restrict__ ids,
                                               float* __restrict__ h) {
    int t = blockIdx.x;
    int id = ids[t];
    const float* src = embed + (size_t)id * DIM;
    float* dst = h + (size_t)t * DIM;
    for (int d = threadIdx.x; d < DIM; d += 256) dst[d] = src[d];
}

// ====================== fused add + RMSNorm ======================
// mode 0: v = h;           resid = v
// mode 1: v = h + resid;   resid = v
// mode 2: v = resid        (h unused)
__global__ __launch_bounds__(256) void k_add_rmsnorm(const float* __restrict__ h,
                                                     float* __restrict__ resid,
                                                     const float* __restrict__ w,
                                                     float* __restrict__ out, int mode) {
    int t = blockIdx.x;
    int tid = threadIdx.x;
    __shared__ float red[256];
    float v[8];
    float ss = 0.f;
    #pragma unroll
    for (int j = 0; j < 8; j++) {
        int d = tid + j * 256;
        float val;
        if (mode == 0)      val = h[t*DIM + d];
        else if (mode == 1) val = h[t*DIM + d] + resid[t*DIM + d];
        else                val = resid[t*DIM + d];
        if (mode != 2) resid[t*DIM + d] = val;
        v[j] = val;
        ss += val * val;
    }
    red[tid] = ss; __syncthreads();
    for (int s = 128; s > 0; s >>= 1) { if (tid < s) red[tid] += red[tid + s]; __syncthreads(); }
    float rs = rsqrtf(red[0] / (float)DIM + EPSF);
    #pragma unroll
    for (int j = 0; j < 8; j++) {
        int d = tid + j * 256;
        out[t*DIM + d] = v[j] * rs * w[d];
    }
}

// ====================== split-bf16 MFMA GEMM ================================
// C[M,N] = A[M,K] @ B[K,N] computed as Ahi*Bhi + Ahi*Blo + Alo*Bhi (fp32 acc).
// 128x128 tile, BK=32, 256 threads = 4 waves (2x2), 4x4 16x16 frags per wave.
// GATHER: A rows via etok[e*T_TOK + i]   (MoE gate_up)
// ADD:    C += result                    (o-proj into residual)
// SCATTER: store row i -> eslot[e*T+i] row of C, scaled by ew[e*T+i] (MoE down)
template<int GATHER, int ADD, int SCATTER>
__global__ __launch_bounds__(256) void k_mfma_gemm(
    const float* __restrict__ A, const float* __restrict__ B, float* __restrict__ C,
    int M, int N, int K,
    long long sA, long long sB, long long sC,
    const int* __restrict__ counts, const int* __restrict__ etok,
    const int* __restrict__ eslot, const float* __restrict__ ew)
{
    constexpr int USE_CNT = (GATHER || SCATTER) ? 1 : 0;
    const int e = blockIdx.z;
    const int nrows = USE_CNT ? counts[e] : M;
    const int i0 = blockIdx.y * 128;
    if (i0 >= nrows) return;           // uniform early-exit, before any barrier
    const int n0 = blockIdx.x * 128;
    const float* Ab = A + (size_t)e * sA;
    const float* Bb = B + (size_t)e * sB;
    float* Cb = C + (size_t)e * sC;

    // [row][k] bf16 tiles; 64B row stride keeps ds_read_b128 aligned and
    // the (16 rows x 4 k-quads) fragment read bank-balanced.
    __shared__ __align__(16) unsigned short Ahi[128][32];
    __shared__ __align__(16) unsigned short Alo[128][32];
    __shared__ __align__(16) unsigned short Bhi[128][32];   // transposed: [n][k]
    __shared__ __align__(16) unsigned short Blo[128][32];
    __shared__ __align__(16) float Btmp[32][128];           // fp32 staging for transpose
    __shared__ int toks[128];

    const int tid = threadIdx.x;
    const int lane = tid & 63;
    const int wid = tid >> 6;
    const int wm = (wid >> 1) * 64;
    const int wn = (wid & 1) * 64;
    const int lr = lane & 15;
    const int lk = (lane >> 4) * 8;
    const int lq = (lane >> 4) * 4;

    if (GATHER) {
        if (tid < 128) {
            int i = i0 + tid;
            toks[tid] = (i < nrows) ? etok[e * T_TOK + i] : etok[e * T_TOK + i0];
        }
        __syncthreads();
    }

    f32x4 zero4 = {0.f, 0.f, 0.f, 0.f};
    f32x4 acc[4][4];
    #pragma unroll
    for (int a = 0; a < 4; a++)
        #pragma unroll
        for (int b = 0; b < 4; b++) acc[a][b] = zero4;

    for (int k0 = 0; k0 < K; k0 += 32) {
        // ---- stage A: 128 rows x 32 k, fp32 -> hi/lo bf16, coalesced float4
        #pragma unroll
        for (int it = 0; it < 4; ++it) {
            int i = tid + it * 256;            // 0..1023
            int r = i >> 3, seg = (i & 7) * 4; // 8 float4 per row
            const float* ap;
            if (GATHER) ap = Ab + (size_t)toks[r] * K + k0 + seg;
            else        ap = Ab + (size_t)(i0 + r) * K + k0 + seg;
            float4 v = *(const float4*)ap;
            unsigned short h0 = f2bf(v.x), h1 = f2bf(v.y), h2 = f2bf(v.z), h3 = f2bf(v.w);
            unsigned short l0 = f2bf(v.x - bf2f(h0)), l1 = f2bf(v.y - bf2f(h1));
            unsigned short l2 = f2bf(v.z - bf2f(h2)), l3 = f2bf(v.w - bf2f(h3));
            *(ushort4*)&Ahi[r][seg] = make_ushort4(h0, h1, h2, h3);
            *(ushort4*)&Alo[r][seg] = make_ushort4(l0, l1, l2, l3);
        }
        // ---- stage B1: 32 k x 128 n fp32 tile, coalesced float4 -> LDS scratch
        #pragma unroll
        for (int it = 0; it < 4; ++it) {
            int q = tid + it * 256;
            int kk = q >> 5, ns = (q & 31) * 4;
            *(float4*)&Btmp[kk][ns] = *(const float4*)(Bb + (size_t)(k0 + kk) * N + n0 + ns);
        }
        __syncthreads();
        // ---- stage B2: transpose + split into [n][k] bf16 (bank-balanced)
        #pragma unroll
        for (int it = 0; it < 2; ++it) {
            int p = tid + it * 256;            // 512 tasks: (n, k-quad)
            int kb = p & 3, n = p >> 2;
            unsigned short hh[8], ll[8];
            #pragma unroll
            for (int j = 0; j < 8; ++j) {
                float v = Btmp[kb * 8 + j][n];
                hh[j] = f2bf(v);
                ll[j] = f2bf(v - bf2f(hh[j]));
            }
            *(ushort4*)&Bhi[n][kb*8]   = make_ushort4(hh[0], hh[1], hh[2], hh[3]);
            *(ushort4*)&Bhi[n][kb*8+4] = make_ushort4(hh[4], hh[5], hh[6], hh[7]);
            *(ushort4*)&Blo[n][kb*8]   = make_ushort4(ll[0], ll[1], ll[2], ll[3]);
            *(ushort4*)&Blo[n][kb*8+4] = make_ushort4(ll[4], ll[5], ll[6], ll[7]);
        }
        __syncthreads();
        // ---- fragments + MFMA: 16 ds_read_b128 + 48 mfma per wave
        s16x8 ah[4], al[4];
        #pragma unroll
        for (int mt = 0; mt < 4; ++mt) {
            int row = wm + mt * 16 + lr;
            ah[mt] = *(const s16x8*)&Ahi[row][lk];
            al[mt] = *(const s16x8*)&Alo[row][lk];
        }
        #pragma unroll
        for (int nt = 0; nt < 4; ++nt) {
            int col = wn + nt * 16 + lr;
            s16x8 bh = *(const s16x8*)&Bhi[col][lk];
            s16x8 bl = *(const s16x8*)&Blo[col][lk];
            #pragma unroll
            for (int mt = 0; mt < 4; ++mt) {
                acc[mt][nt] = __builtin_amdgcn_mfma_f32_16x16x32_bf16(ah[mt], bh, acc[mt][nt], 0, 0, 0);
                acc[mt][nt] = __builtin_amdgcn_mfma_f32_16x16x32_bf16(ah[mt], bl, acc[mt][nt], 0, 0, 0);
                acc[mt][nt] = __builtin_amdgcn_mfma_f32_16x16x32_bf16(al[mt], bh, acc[mt][nt], 0, 0, 0);
            }
        }
        __syncthreads();
    }

    // ---- epilogue: D layout col=lane&15, row=(lane>>4)*4+reg (m89-verified)
    #pragma unroll
    for (int mt = 0; mt < 4; ++mt) {
        #pragma unroll
        for (int r = 0; r < 4; ++r) {
            int lrow = wm + mt * 16 + lq + r;
            int i = i0 + lrow;
            if (USE_CNT && i >= nrows) continue;
            if (SCATTER) {
                int sl = eslot[e * T_TOK + i];
                float w = ew[e * T_TOK + i];
                #pragma unroll
                for (int nt = 0; nt < 4; ++nt)
                    Cb[(size_t)sl * N + n0 + wn + nt * 16 + lr] = w * acc[mt][nt][r];
            } else if (ADD) {
                #pragma unroll
                for (int nt = 0; nt < 4; ++nt) {
                    size_t idx = (size_t)i * N + n0 + wn + nt * 16 + lr;
                    Cb[idx] += acc[mt][nt][r];
                }
            } else {
                #pragma unroll
                for (int nt = 0; nt < 4; ++nt)
                    Cb[(size_t)i * N + n0 + wn + nt * 16 + lr] = acc[mt][nt][r];
            }
        }
    }
}

// ====================== per-head q/k RMSNorm + RoPE (in place) ==============
__global__ __launch_bounds__(128) void k_qknorm_rope(float* __restrict__ qkv,
                                                     const float* __restrict__ qw,
                                                     const float* __restrict__ kw,
                                                     const int* __restrict__ pos_ids) {
    int t = blockIdx.x, hh = blockIdx.y, tid = threadIdx.x;
    __shared__ float red[128];
    __shared__ float buf[128];
    float* ptr; const float* w;
    if (hh < NHQ) { ptr = qkv + (size_t)t*QKV_N + hh*HD;            w = qw; }
    else          { ptr = qkv + (size_t)t*QKV_N + NHQ*HD + (hh-NHQ)*HD; w = kw; }
    float v = ptr[tid];
    red[tid] = v * v; __syncthreads();
    for (int s = 64; s > 0; s >>= 1) { if (tid < s) red[tid] += red[tid + s]; __syncthreads(); }
    float rs = rsqrtf(red[0] / (float)HD + EPSF);
    float nv = v * rs * w[tid];
    buf[tid] = nv; __syncthreads();
    float other = (tid < 64) ? -buf[tid + 64] : buf[tid - 64];
    int i = tid & 63;
    float pos = (float)pos_ids[t];
    float inv_freq = exp2f(-(float)(2*i) * (19.93156856932417f / 128.f));
    float ang = pos * inv_freq;
    float sn, cs;
    sincosf(ang, &sn, &cs);
    ptr[tid] = nv * cs + other * sn;
}

// ====================== attention: one block per (t, q-head) ================
__global__ __launch_bounds__(256) void k_attn(const float* __restrict__ qkv,
                                              float* __restrict__ out) {
    int t = blockIdx.x, hq = blockIdx.y, tid = threadIdx.x;
    int g = hq >> 2;  // HQ/HKV = 4
    __shared__ float qv[HD];
    __shared__ float sc[T_TOK];
    __shared__ float red[256];
    const float* qp = qkv + (size_t)t*QKV_N + hq*HD;
    if (tid < HD) qv[tid] = qp[tid];
    __syncthreads();
    int nk = t + 1;
    const float scale = 0.08838834764831845f;  // 1/sqrt(128)
    float lm = -1e30f;
    for (int j = tid; j < nk; j += 256) {
        const float* kp = qkv + (size_t)j*QKV_N + NHQ*HD + g*HD;
        float dot = 0.f;
        #pragma unroll 8
        for (int d = 0; d < HD; d++) dot += qv[d] * kp[d];
        dot *= scale;
        sc[j] = dot;
        lm = fmaxf(lm, dot);
    }
    red[tid] = lm; __syncthreads();
    for (int s = 128; s > 0; s >>= 1) { if (tid < s) red[tid] = fmaxf(red[tid], red[tid + s]); __syncthreads(); }
    float m = red[0];
    __syncthreads();
    float ls = 0.f;
    for (int j = tid; j < nk; j += 256) {
        float e = __expf(sc[j] - m);
        sc[j] = e; ls += e;
    }
    red[tid] = ls; __syncthreads();
    for (int s = 128; s > 0; s >>= 1) { if (tid < s) red[tid] += red[tid + s]; __syncthreads(); }
    float inv_l = 1.f / red[0];
    if (tid < HD) {
        const float* vp = qkv + (NHQ + NHKV)*HD + g*HD + tid;
        float acc = 0.f;
        for (int j = 0; j < nk; j++) acc += sc[j] * vp[(size_t)j * QKV_N];
        out[(size_t)t*(NHQ*HD) + hq*HD + tid] = acc * inv_l;
    }
}

// ====================== router: gate logits, softmax, top-2, gather =========
__global__ __launch_bounds__(256) void k_gate(const float* __restrict__ x,
                                              const float* __restrict__ gw,
                                              int* counts, int* etok, int* eslot,
                                              float* ew) {
    int t = blockIdx.x, tid = threadIdx.x;
    float acc[NE] = {};
    for (int d = tid; d < DIM; d += 256) {
        float xv = x[t*DIM + d];
        #pragma unroll
        for (int e = 0; e < NE; e++) acc[e] += xv * gw[d*NE + e];
    }
    __shared__ float red[256];
    __shared__ float logits[NE];
    for (int e = 0; e < NE; e++) {
        red[tid] = acc[e]; __syncthreads();
        for (int s = 128; s > 0; s >>= 1) { if (tid < s) red[tid] += red[tid + s]; __syncthreads(); }
        if (tid == 0) logits[e] = red[0];
        __syncthreads();
    }
    if (tid == 0) {
        int i1 = 0; float m1 = logits[0];
        for (int e = 1; e < NE; e++) if (logits[e] > m1) { m1 = logits[e]; i1 = e; }
        int i2 = -1; float m2 = -1e30f;
        for (int e = 0; e < NE; e++) { if (e == i1) continue; if (logits[e] > m2) { m2 = logits[e]; i2 = e; } }
        float e2 = expf(m2 - m1);
        float sum = 1.f + e2;
        float w1 = 1.f / sum, w2 = e2 / sum;
        int s1 = atomicAdd(&counts[i1], 1);
        etok[i1*T_TOK + s1] = t; eslot[i1*T_TOK + s1] = t*2;     ew[i1*T_TOK + s1] = w1;
        int s2 = atomicAdd(&counts[i2], 1);
        etok[i2*T_TOK + s2] = t; eslot[i2*T_TOK + s2] = t*2 + 1; ew[i2*T_TOK + s2] = w2;
    }
}

__global__ void k_zero_counts(int* counts) { if (threadIdx.x < NE) counts[threadIdx.x] = 0; }

// ====================== SiLU(g) * u from packed gu buffer ===================
__global__ __launch_bounds__(256) void k_silu(const float* __restrict__ gu,
                                              float* __restrict__ act) {
    int idx = blockIdx.x * 256 + threadIdx.x;   // NE*T_TOK*NF total
    int f = idx % NF;
    int row = idx / NF;
    float g = gu[(size_t)row * (2*NF) + f];
    float u = gu[(size_t)row * (2*NF) + NF + f];
    act[idx] = g / (1.f + expf(-g)) * u;
}

// h[t,d] = down[2t,d] + down[2t+1,d]
__global__ __launch_bounds__(256) void k_combine(const float* __restrict__ down,
                                                 float* __restrict__ h) {
    int idx = blockIdx.x * 256 + threadIdx.x;
    int t = idx >> 11;
    int d = idx & 2047;
    h[idx] = down[(size_t)(t*2)*DIM + d] + down[(size_t)(t*2 + 1)*DIM + d];
}

// ============================================================================
extern "C" void kernel_launch(void* const* d_in, const int* in_sizes, int n_in,
                              void* d_out, int out_size, void* d_ws, size_t ws_size,
                              hipStream_t stream) {
    const float* embed        = (const float*)d_in[0];
    const float* ln1_w        = (const float*)d_in[1];
    const float* qkv_w        = (const float*)d_in[2];
    const float* q_norm_w     = (const float*)d_in[3];
    const float* k_norm_w     = (const float*)d_in[4];
    const float* o_w          = (const float*)d_in[5];
    const float* ln2_w        = (const float*)d_in[6];
    const float* gate_w       = (const float*)d_in[7];
    const float* w_gate_up    = (const float*)d_in[8];
    const float* w_down       = (const float*)d_in[9];
    const float* final_norm_w = (const float*)d_in[10];
    const int*   input_ids    = (const int*)d_in[11];
    const int*   position_ids = (const int*)d_in[12];

    char* ws = (char*)d_ws;
    float* resid    = (float*)ws; ws += (size_t)T_TOK*DIM*4;          //  8 MB
    float* x        = (float*)ws; ws += (size_t)T_TOK*DIM*4;          //  8 MB
    float* qkv      = (float*)ws; ws += (size_t)T_TOK*QKV_N*4;        // 12 MB
    float* attn_out = (float*)ws; ws += (size_t)T_TOK*DIM*4;          //  8 MB
    float* h        = (float*)ws; ws += (size_t)T_TOK*DIM*4;          //  8 MB
    float* gu       = (float*)ws; ws += (size_t)NE*T_TOK*2*NF*4;      // 50 MB
    float* act      = (float*)ws; ws += (size_t)NE*T_TOK*NF*4;        // 25 MB
    float* down     = gu;   // alias: gu is dead once act is computed
    int*   counts   = (int*)ws;   ws += 256;
    int*   etok     = (int*)ws;   ws += (size_t)NE*T_TOK*4;
    int*   eslot    = (int*)ws;   ws += (size_t)NE*T_TOK*4;
    float* ew       = (float*)ws; ws += (size_t)NE*T_TOK*4;

    k_embed<<<T_TOK, 256, 0, stream>>>(embed, input_ids, h);

    for (int l = 0; l < 2; l++) {
        k_add_rmsnorm<<<T_TOK, 256, 0, stream>>>(h, resid, ln1_w + l*DIM, x, l == 0 ? 0 : 1);
        // QKV projection
        k_mfma_gemm<0,0,0><<<dim3(QKV_N/128, T_TOK/128, 1), 256, 0, stream>>>(
            x, qkv_w + (size_t)l*DIM*QKV_N, qkv, T_TOK, QKV_N, DIM,
            0, 0, 0, nullptr, nullptr, nullptr, nullptr);
        k_qknorm_rope<<<dim3(T_TOK, NHQ + NHKV), 128, 0, stream>>>(
            qkv, q_norm_w + l*HD, k_norm_w + l*HD, position_ids);
        k_attn<<<dim3(T_TOK, NHQ), 256, 0, stream>>>(qkv, attn_out);
        // O projection, accumulated into residual
        k_mfma_gemm<0,1,0><<<dim3(DIM/128, T_TOK/128, 1), 256, 0, stream>>>(
            attn_out, o_w + (size_t)l*DIM*DIM, resid, T_TOK, DIM, DIM,
            0, 0, 0, nullptr, nullptr, nullptr, nullptr);
        k_add_rmsnorm<<<T_TOK, 256, 0, stream>>>(nullptr, resid, ln2_w + l*DIM, x, 2);
        k_zero_counts<<<1, 64, 0, stream>>>(counts);
        k_gate<<<T_TOK, 256, 0, stream>>>(x, gate_w + (size_t)l*DIM*NE, counts, etok, eslot, ew);
        // MoE gate_up: gathered rows of x  @ w_gate_up[e]  -> gu
        k_mfma_gemm<1,0,0><<<dim3((2*NF)/128, T_TOK/128, NE), 256, 0, stream>>>(
            x, w_gate_up + (size_t)l*NE*DIM*2*NF, gu, T_TOK, 2*NF, DIM,
            0, (long long)DIM*2*NF, (long long)T_TOK*2*NF,
            counts, etok, nullptr, nullptr);
        k_silu<<<(NE*T_TOK*NF)/256, 256, 0, stream>>>(gu, act);
        // MoE down: act[e] @ w_down[e] -> scattered, weighted slots
        k_mfma_gemm<0,0,1><<<dim3(DIM/128, T_TOK/128, NE), 256, 0, stream>>>(
            act, w_down + (size_t)l*NE*NF*DIM, down, T_TOK, DIM, NF,
            (long long)T_TOK*NF, (long long)NF*DIM, 0,
            counts, nullptr, eslot, ew);
        k_combine<<<(T_TOK*DIM)/256, 256, 0, stream>>>(down, h);
    }

    k_add_rmsnorm<<<T_TOK, 256, 0, stream>>>(h, resid, final_norm_w, (float*)d_out, 1);
}